// Round 11
// baseline (45.285 us; speedup 1.0000x reference)
//
#include <hip/hip_runtime.h>

// SmileResampler: out[b,bh,h,w] = lerp over band axis of x at
// iy = clip(bh + clip(ws[b,bh,w],-2,2), 0, 127) * (128/127) - 0.5
// Shapes: x (4,128,256,256) f32, ws (4,128,256) f32, out same as x.
//
// Block = (b, h, 32-band tile), 512 threads, 4-window split-phase staging.
// Wave v owns band bh0 + g*8 + v for groups g=0..3, cols lane + 64*j.
// Staged rows (38 + 1 dummy) split into chunks:
//   A = rows 0..15 (2 slots/wave), B = 16..23, C = 24..31, D = 32..39
//   (1 slot/wave; D rows 38,39 -> dummy row). Group g needs local rows
//   [g*8 .. g*8+13] (subset of chunks <= g+1).
// Issue order per wave: A(2) ws0(4) B(1) ws1(4) C(1) ws2(4) D(1) ws3(4)
//   = 21 VMEM loads; compute window g issues 4 stores.
// Counted waits (vmcnt retires in issue order; stores accounted):
//   w1: need A+ws0   -> 15 outstanding allowed -> vmcnt(15)
//   w2: need ..B+ws1 -> 25 issued - 11 retired -> vmcnt(14)
//   w3: need ..C+ws2 -> 29 issued - 16 retired -> vmcnt(13)
//   w4: need ..D+ws3 -> 33 issued - 21 retired -> vmcnt(12)
// Each wait + raw s_barrier; all waves run all windows (no divergence).
// XCD-chunked swizzle keeps a (b,h)'s 4 tiles on one XCD (halo -> L2 hits).

#define BH_  128
#define H_   256
#define W_   256
#define TB    32          // output bands per block
#define NLDS (TB + 6)     // 38 real staged rows

__global__ __launch_bounds__(512) void smile_kernel(
    const float* __restrict__ x,
    const float* __restrict__ ws,
    float* __restrict__ out)
{
    __shared__ float tile[NLDS + 1][W_];   // +1 dummy row = 39 KiB -> 4 blk/CU

    // XCD-chunked bijective swizzle (nwg = 4096, 8 XCDs, chunk = 512)
    const int bid0 = blockIdx.x;
    const int bid  = (bid0 & 7) * 512 + (bid0 >> 3);

    const int tileI = bid & 3;             // 4 tiles per (b,h)
    const int rem   = bid >> 2;
    const int h   = rem & (H_ - 1);
    const int b   = rem >> 8;
    const int bh0 = tileI * TB;

    const int t    = threadIdx.x;
    const int wave = t >> 6;               // 0..7
    const int lane = t & 63;

    const float* __restrict__ xsrc = x + (size_t)b * (BH_ * H_ * W_) + h * W_;

    auto STAGE_ROW = [&](int i) {          // local row i (>=NLDS -> dummy)
        const bool rl = (i < NLDS);
        const int band = min(max(bh0 - 3 + (rl ? i : 0), 0), BH_ - 1);
        const float* gp = xsrc + (size_t)band * (H_ * W_) + lane * 4;
        __builtin_amdgcn_global_load_lds(
            (const __attribute__((address_space(1))) void*)gp,
            (__attribute__((address_space(3))) void*)&tile[rl ? i : NLDS][0],
            16, 0, 0);
    };

    // ws base for group g: band bh0 + g*8 + wave, col lane + 64*j
    const float* __restrict__ wsb =
        ws + (size_t)(b * BH_ + bh0 + wave) * W_ + lane;
    float s[4][4];

    // ---- interleaved issue: A ws0 B ws1 C ws2 D ws3 ----
    STAGE_ROW(wave);  STAGE_ROW(wave + 8);                 // A
    __builtin_amdgcn_sched_barrier(0);
#pragma unroll
    for (int j = 0; j < 4; ++j) s[0][j] = wsb[0 * 8 * W_ + j * 64];
    __builtin_amdgcn_sched_barrier(0);
    STAGE_ROW(wave + 16);                                  // B
    __builtin_amdgcn_sched_barrier(0);
#pragma unroll
    for (int j = 0; j < 4; ++j) s[1][j] = wsb[1 * 8 * W_ + j * 64];
    __builtin_amdgcn_sched_barrier(0);
    STAGE_ROW(wave + 24);                                  // C
    __builtin_amdgcn_sched_barrier(0);
#pragma unroll
    for (int j = 0; j < 4; ++j) s[2][j] = wsb[2 * 8 * W_ + j * 64];
    __builtin_amdgcn_sched_barrier(0);
    STAGE_ROW(wave + 32);                                  // D
    __builtin_amdgcn_sched_barrier(0);
#pragma unroll
    for (int j = 0; j < 4; ++j) s[3][j] = wsb[3 * 8 * W_ + j * 64];
    __builtin_amdgcn_sched_barrier(0);

    const float scale = (float)(128.0 / 127.0);
    float* __restrict__ outbase =
        out + (((size_t)b * BH_ + bh0 + wave) * H_ + h) * W_ + lane;

    auto COMPUTE = [&](int g) {
        const int bh = bh0 + g * 8 + wave;
        float* __restrict__ outp = outbase + (size_t)(g * 8) * (H_ * W_);
#pragma unroll
        for (int j = 0; j < 4; ++j) {
            const int w = lane + j * 64;
            float sc      = fminf(fmaxf(s[g][j], -2.0f), 2.0f);
            float shifted = fminf(fmaxf((float)bh + sc, 0.0f),
                                  (float)(BH_ - 1));
            float iy      = fmaf(shifted, scale, -0.5f);
            float i0f     = floorf(iy);
            float frac    = iy - i0f;
            int   i0      = (int)i0f;
            int   r0      = min(max(i0, 0), BH_ - 1) - bh0 + 3;
            int   r1      = min(i0 + 1, BH_ - 1) - bh0 + 3;
            float x0 = tile[r0][w];
            float x1 = tile[r1][w];
            __builtin_nontemporal_store(fmaf(frac, x1 - x0, x0),
                                        outp + j * 64);
        }
    };

    asm volatile("s_waitcnt vmcnt(15)" ::: "memory");   // A + ws0 landed
    __builtin_amdgcn_s_barrier();
    __builtin_amdgcn_sched_barrier(0);
    COMPUTE(0);
    __builtin_amdgcn_sched_barrier(0);

    asm volatile("s_waitcnt vmcnt(14)" ::: "memory");   // ..B + ws1 landed
    __builtin_amdgcn_s_barrier();
    __builtin_amdgcn_sched_barrier(0);
    COMPUTE(1);
    __builtin_amdgcn_sched_barrier(0);

    asm volatile("s_waitcnt vmcnt(13)" ::: "memory");   // ..C + ws2 landed
    __builtin_amdgcn_s_barrier();
    __builtin_amdgcn_sched_barrier(0);
    COMPUTE(2);
    __builtin_amdgcn_sched_barrier(0);

    asm volatile("s_waitcnt vmcnt(12)" ::: "memory");   // ..D + ws3 landed
    __builtin_amdgcn_s_barrier();
    __builtin_amdgcn_sched_barrier(0);
    COMPUTE(3);
}

extern "C" void kernel_launch(void* const* d_in, const int* in_sizes, int n_in,
                              void* d_out, int out_size, void* d_ws, size_t ws_size,
                              hipStream_t stream) {
    const float* x  = (const float*)d_in[0];
    const float* ws = (const float*)d_in[1];
    float* out = (float*)d_out;

    const int grid = 4 * H_ * (BH_ / TB);   // 4096, multiple of 8 (swizzle)
    smile_kernel<<<grid, 512, 0, stream>>>(x, ws, out);
}